// Round 4
// baseline (450.529 us; speedup 1.0000x reference)
//
#include <hip/hip_runtime.h>

#define S 132                 // padded LDS row stride (floats) for gemm tiles
#define SCALE 10.0f           // 1 / TEMPERATURE
#define EPS_MARGIN 0.009f     // > 2 * bf16 unit-dot error bound (2*0.004)
#define PAIR_CAP 32768

typedef __attribute__((ext_vector_type(8))) short short8;
typedef __attribute__((ext_vector_type(4))) float floatx4;

#define MFMA16(a, b, c) __builtin_amdgcn_mfma_f32_16x16x32_bf16((a), (b), (c), 0, 0, 0)

// ---------- helpers ----------
__device__ __forceinline__ unsigned int ordered_bits(float f) {
    unsigned int b = __float_as_uint(f);
    return (b & 0x80000000u) ? ~b : (b | 0x80000000u);
}
__device__ __forceinline__ float from_ordered(unsigned int u) {
    return __uint_as_float((u & 0x80000000u) ? (u ^ 0x80000000u) : ~u);
}
__device__ __forceinline__ short bf_rne(float x) {   // fp32 -> bf16 bits, RNE
    unsigned int u = __float_as_uint(x);
    return (short)((u + 0x7FFFu + ((u >> 16) & 1u)) >> 16);
}
__device__ __forceinline__ float bf2f(short s) {
    return __uint_as_float(((unsigned int)(unsigned short)s) << 16);
}

// ---------- K1: l2-normalize p1,p2 -> pn fp32; init best/paircnt/sums --------
__global__ void k_prep(const float* __restrict__ p1, const float* __restrict__ p2,
                       float* __restrict__ pn, unsigned long long* __restrict__ best,
                       unsigned int* __restrict__ paircnt, float* __restrict__ sums) {
    int row = blockIdx.x;               // 0..4095
    int t = threadIdx.x;                // 0..63
    const float* src = (row < 2048) ? (p1 + (size_t)row * 128)
                                    : (p2 + (size_t)(row - 2048) * 128);
    float2 v = ((const float2*)src)[t];
    float ss = v.x * v.x + v.y * v.y;
    #pragma unroll
    for (int o = 32; o; o >>= 1) ss += __shfl_xor(ss, o);
    float inv = 1.0f / sqrtf(ss);
    float2 o2; o2.x = v.x * inv; o2.y = v.y * inv;
    ((float2*)(pn + (size_t)row * 128))[t] = o2;
    if (t == 0) { best[row] = 0ULL; if (row == 0) *paircnt = 0u; }
    if (row < 128) sums[row * 64 + t] = 0.0f;
}

// ---------- K2: queue fp32 -> qb bf16 ----------
__global__ void k_qcvt(const float* __restrict__ queue, short* __restrict__ qb) {
    size_t i = ((size_t)blockIdx.x * 256 + threadIdx.x) * 8;
    float4 f0 = *(const float4*)(queue + i);
    float4 f1 = *(const float4*)(queue + i + 4);
    short8 o;
    o[0] = bf_rne(f0.x); o[1] = bf_rne(f0.y); o[2] = bf_rne(f0.z); o[3] = bf_rne(f0.w);
    o[4] = bf_rne(f1.x); o[5] = bf_rne(f1.y); o[6] = bf_rne(f1.z); o[7] = bf_rne(f1.w);
    *(short8*)(qb + i) = o;
}

// ---------- K3: single bf16 MFMA screen -> per-(row,128q-chunk) max (u16) ----
// grid (64 rowblocks, 16 qsplits), 256 thr. Wave: 64 rows x 1024 q, K=128.
// Chunk max stored rounded UP as monotone u16 (no false negatives downstream).
__global__ __launch_bounds__(256, 4) void k_screen(const float* __restrict__ pn,
                                                   const short* __restrict__ qb,
                                                   unsigned short* __restrict__ cm) {
    int tid = threadIdx.x;
    int lane = tid & 63, wv = tid >> 6;
    int n16 = lane & 15, quad = lane >> 4;
    int rowbase = blockIdx.x * 64;
    int qstart = blockIdx.y * 4096 + wv * 1024;

    short8 A[4][4];                     // 64 VGPRs
    #pragma unroll
    for (int rf = 0; rf < 4; ++rf) {
        const float* ap = pn + (size_t)(rowbase + rf * 16 + n16) * 128 + quad * 8;
        #pragma unroll
        for (int k = 0; k < 4; ++k) {
            float4 f0 = *(const float4*)(ap + 32 * k);
            float4 f1 = *(const float4*)(ap + 32 * k + 4);
            short8 a;
            a[0] = bf_rne(f0.x); a[1] = bf_rne(f0.y); a[2] = bf_rne(f0.z); a[3] = bf_rne(f0.w);
            a[4] = bf_rne(f1.x); a[5] = bf_rne(f1.y); a[6] = bf_rne(f1.z); a[7] = bf_rne(f1.w);
            A[rf][k] = a;
        }
    }

    float rmaxc[4][4];
    #pragma unroll
    for (int rf = 0; rf < 4; ++rf)
        #pragma unroll
        for (int r = 0; r < 4; ++r) rmaxc[rf][r] = -1e30f;

    const short* lp = qb + (size_t)(qstart + n16) * 128 + quad * 8;
    short8 bc0 = *(const short8*)(lp), bc1 = *(const short8*)(lp + 32),
           bc2 = *(const short8*)(lp + 64), bc3 = *(const short8*)(lp + 96);
    floatx4 zero = {0.0f, 0.0f, 0.0f, 0.0f};

    for (int t = 0; t < 64; ++t) {
        const short* nlp = lp + 2048;   // prefetch next 16-q tile (tail stays in ws)
        short8 bn0 = *(const short8*)(nlp), bn1 = *(const short8*)(nlp + 32),
               bn2 = *(const short8*)(nlp + 64), bn3 = *(const short8*)(nlp + 96);
        #pragma unroll
        for (int rf = 0; rf < 4; ++rf) {
            floatx4 acc = MFMA16(A[rf][0], bc0, zero);
            acc = MFMA16(A[rf][1], bc1, acc);
            acc = MFMA16(A[rf][2], bc2, acc);
            acc = MFMA16(A[rf][3], bc3, acc);
            #pragma unroll
            for (int r = 0; r < 4; ++r) rmaxc[rf][r] = fmaxf(rmaxc[rf][r], acc[r]);
        }
        if ((t & 7) == 7) {             // 128-q chunk boundary
            int cidx = (qstart >> 7) + (t >> 3);
            #pragma unroll
            for (int rf = 0; rf < 4; ++rf)
                #pragma unroll
                for (int r = 0; r < 4; ++r) {
                    float v = rmaxc[rf][r];
                    v = fmaxf(v, __shfl_xor(v, 1));
                    v = fmaxf(v, __shfl_xor(v, 2));
                    v = fmaxf(v, __shfl_xor(v, 4));
                    v = fmaxf(v, __shfl_xor(v, 8));
                    if (n16 == 0) {
                        int row = rowbase + rf * 16 + quad * 4 + r;
                        unsigned int s = (ordered_bits(v) >> 16) + 1u;
                        if (s > 0xFFFFu) s = 0xFFFFu;
                        cm[(size_t)row * 512 + cidx] = (unsigned short)s;
                    }
                    rmaxc[rf][r] = -1e30f;
                }
        }
        bc0 = bn0; bc1 = bn1; bc2 = bn2; bc3 = bn3;
        lp = nlp;
    }
}

// ---------- K4: per-row max over 512 chunk maxes -> u16 threshold ----------
__global__ void k_rowmax(const unsigned short* __restrict__ cm,
                         unsigned int* __restrict__ thrbuf) {
    int row = blockIdx.x;               // 0..4095
    int l = threadIdx.x;                // 0..63
    uint4 v = ((const uint4*)(cm + (size_t)row * 512))[l];
    unsigned int m = 0;
    m = max(m, v.x & 0xFFFFu); m = max(m, v.x >> 16);
    m = max(m, v.y & 0xFFFFu); m = max(m, v.y >> 16);
    m = max(m, v.z & 0xFFFFu); m = max(m, v.z >> 16);
    m = max(m, v.w & 0xFFFFu); m = max(m, v.w >> 16);
    #pragma unroll
    for (int o = 32; o; o >>= 1) m = max(m, __shfl_xor(m, o));
    if (l == 0) {
        float vmax = from_ordered((m - 1u) << 16);   // <= true bf16 rowmax
        thrbuf[row] = ordered_bits(vmax - EPS_MARGIN) >> 16;
    }
}

// ---------- K5: compact flagged (row,chunk) pairs ----------
__global__ void k_compact(const unsigned short* __restrict__ cm,
                          const unsigned int* __restrict__ thrbuf,
                          unsigned int* __restrict__ paircnt,
                          unsigned int* __restrict__ pairs) {
    int idx = blockIdx.x * 256 + threadIdx.x;   // 0 .. 2M-1
    unsigned int s = cm[idx];
    unsigned int row = (unsigned int)idx >> 9;
    if (s >= thrbuf[row]) {
        unsigned int pos = atomicAdd(paircnt, 1u);
        if (pos < PAIR_CAP) pairs[pos] = (unsigned int)idx;
    }
}

// ---------- K6: exact fp32 re-rank of flagged chunks ----------
// One workgroup per pair (grid-stride). Stage 64 q-rows in stride-129 LDS
// (conflict-free), 256 thr = 64 q x 4 K-quarters, packed atomicMax per row.
__global__ __launch_bounds__(256) void k_exact(const float* __restrict__ pn,
                                               const float* __restrict__ queue,
                                               const unsigned int* __restrict__ paircnt,
                                               const unsigned int* __restrict__ pairs,
                                               unsigned long long* __restrict__ best) {
    __shared__ float qlds[64 * 129];
    __shared__ float plds[128];
    __shared__ float partial[256];
    int tid = threadIdx.x;
    unsigned int n = *paircnt; if (n > PAIR_CAP) n = PAIR_CAP;
    for (unsigned int p = blockIdx.x; p < n; p += gridDim.x) {
        unsigned int pr = pairs[p];
        unsigned int row = pr >> 9;
        unsigned int qb0 = (pr & 511u) << 7;
        __syncthreads();                 // LDS reuse guard across pairs
        if (tid < 32) ((float4*)plds)[tid] = ((const float4*)(pn + (size_t)row * 128))[tid];
        #pragma unroll
        for (int h = 0; h < 2; ++h) {
            __syncthreads();             // plds ready / prev compute drained
            const float4* qs = (const float4*)(queue + (size_t)(qb0 + h * 64) * 128);
            for (int i = tid; i < 2048; i += 256) {
                float4 v = qs[i];
                float* d = &qlds[(i >> 5) * 129 + (i & 31) * 4];
                d[0] = v.x; d[1] = v.y; d[2] = v.z; d[3] = v.w;
            }
            __syncthreads();
            int q = tid & 63, kq = tid >> 6;
            const float* qr = &qlds[q * 129 + kq * 32];
            const float* pp = &plds[kq * 32];
            float s = 0.0f;
            #pragma unroll
            for (int k = 0; k < 32; ++k) s += pp[k] * qr[k];
            partial[tid] = s;
            __syncthreads();
            if (tid < 64) {
                float d = partial[tid] + partial[tid + 64] + partial[tid + 128] + partial[tid + 192];
                unsigned long long pk = ((unsigned long long)ordered_bits(d) << 32)
                                      | (unsigned long long)(unsigned int)(~(qb0 + h * 64 + tid));
                #pragma unroll
                for (int o = 32; o; o >>= 1) {
                    unsigned long long o2 = __shfl_xor(pk, o);
                    if (o2 > pk) pk = o2;
                }
                if (tid == 0) atomicMax(&best[row], pk);
            }
        }
    }
}

// ---------- K7: gather nn rows from queue -> bf16 ----------
__global__ void k_gather(const float* __restrict__ queue,
                         const unsigned long long* __restrict__ best,
                         short* __restrict__ nnb) {
    int row = blockIdx.x;
    int t = threadIdx.x;
    unsigned int idx = ~(unsigned int)(best[row] & 0xFFFFFFFFull);
    idx &= 0xFFFFu;
    float2 v = ((const float2*)(queue + (size_t)idx * 128))[t];
    unsigned int pk = (unsigned int)(unsigned short)bf_rne(v.x)
                    | ((unsigned int)(unsigned short)bf_rne(v.y) << 16);
    ((unsigned int*)(nnb + (size_t)row * 128))[t] = pk;
}

// ---------- K8: fused A(bf16) @ B(fp32)^T -> exp-partial row/col sums --------
__global__ __launch_bounds__(256) void k_gemm_lse(const short* __restrict__ Ab,
                                                  const float* __restrict__ B,
                                                  float* __restrict__ rowsum,
                                                  float* __restrict__ colsum,
                                                  float* __restrict__ diag) {
    __shared__ __align__(16) float al[64 * S];
    __shared__ __align__(16) float bl[64 * S];
    __shared__ float red[64][17];
    int tid = threadIdx.x;
    const short8* asrc = (const short8*)(Ab + (size_t)blockIdx.x * 64 * 128);
    #pragma unroll
    for (int i = tid; i < 1024; i += 256) {
        short8 v = asrc[i];
        int r = i >> 4, c = (i & 15) * 8;
        float* dst = &al[r * S + c];
        #pragma unroll
        for (int j = 0; j < 8; ++j) dst[j] = bf2f(v[j]);
    }
    const float4* bsrc = (const float4*)(B + (size_t)blockIdx.y * 64 * 128);
    #pragma unroll
    for (int i = tid; i < 2048; i += 256) {
        int r = i >> 5, c = i & 31;
        *(float4*)&bl[r * S + c * 4] = bsrc[i];
    }
    __syncthreads();
    int ty = tid >> 4, tx = tid & 15;
    float acc[4][4] = {};
    #pragma unroll 2
    for (int k = 0; k < 128; k += 4) {
        float4 a[4], b[4];
        #pragma unroll
        for (int i = 0; i < 4; ++i) a[i] = *(const float4*)&al[(ty + 16 * i) * S + k];
        #pragma unroll
        for (int j = 0; j < 4; ++j) b[j] = *(const float4*)&bl[(tx + 16 * j) * S + k];
        #pragma unroll
        for (int i = 0; i < 4; ++i)
            #pragma unroll
            for (int j = 0; j < 4; ++j)
                acc[i][j] += a[i].x * b[j].x + a[i].y * b[j].y +
                             a[i].z * b[j].z + a[i].w * b[j].w;
    }
    int rowbase = blockIdx.x * 64, colbase = blockIdx.y * 64;

    float e[4][4], rs[4], cs[4];
    #pragma unroll
    for (int i = 0; i < 4; ++i) { rs[i] = 0.0f; cs[i] = 0.0f; }
    #pragma unroll
    for (int i = 0; i < 4; ++i)
        #pragma unroll
        for (int j = 0; j < 4; ++j) {
            e[i][j] = __expf(acc[i][j] * SCALE - 10.0f);
            rs[i] += e[i][j];
        }
    #pragma unroll
    for (int j = 0; j < 4; ++j)
        #pragma unroll
        for (int i = 0; i < 4; ++i) cs[j] += e[i][j];

    if (rowbase == colbase && ty == tx) {
        #pragma unroll
        for (int i = 0; i < 4; ++i) diag[rowbase + ty + 16 * i] = acc[i][i];
    }

    #pragma unroll
    for (int i = 0; i < 4; ++i) red[ty + 16 * i][tx] = rs[i];
    __syncthreads();
    if (tid < 64) {
        float s = 0.0f;
        #pragma unroll
        for (int x = 0; x < 16; ++x) s += red[tid][x];
        atomicAdd(&rowsum[rowbase + tid], s);
    }
    __syncthreads();
    #pragma unroll
    for (int j = 0; j < 4; ++j) red[tx + 16 * j][ty] = cs[j];
    __syncthreads();
    if (tid < 64) {
        float s = 0.0f;
        #pragma unroll
        for (int x = 0; x < 16; ++x) s += red[tid][x];
        atomicAdd(&colsum[colbase + tid], s);
    }
}

// ---------- K9: final loss ----------
__global__ void k_final(const float* __restrict__ sums,
                        const float* __restrict__ dg1, const float* __restrict__ dg2,
                        float* __restrict__ out) {
    int idx = blockIdx.x * 256 + threadIdx.x;    // 0..8191
    int seg = idx >> 11, r = idx & 2047;
    float s = sums[seg * 2048 + r];
    float d = (seg < 2) ? dg1[r] : dg2[r];
    out[idx] = 10.0f + logf(s) - d * SCALE;
}

extern "C" void kernel_launch(void* const* d_in, const int* in_sizes, int n_in,
                              void* d_out, int out_size, void* d_ws, size_t ws_size,
                              hipStream_t stream) {
    const float* p1    = (const float*)d_in[0];   // [2048,128]
    const float* p2    = (const float*)d_in[1];   // [2048,128]
    const float* queue = (const float*)d_in[2];   // [65536,128]
    float* out = (float*)d_out;                   // [8192]

    char* w = (char*)d_ws;                        // footprint ~23.3 MiB
    float* pn  = (float*)w;                               // 2 MB  [4096,128] fp32
    short* nnb = (short*)(w + (2u << 20));                // 1 MB  [4096,128] bf16
    short* qb  = (short*)(w + (3u << 20));                // 16 MB [65536,128] bf16
    unsigned short* cm = (unsigned short*)(w + (19u << 20)); // 4 MB [4096,512] u16
    char* b2 = w + (23u << 20);
    unsigned int* thrbuf = (unsigned int*)b2;                       // 16 KB
    unsigned long long* best = (unsigned long long*)(b2 + (16u << 10)); // 32 KB
    unsigned int* paircnt = (unsigned int*)(b2 + (48u << 10));      // 256 B
    unsigned int* pairs = (unsigned int*)(b2 + (64u << 10));        // 128 KB
    float* sums = (float*)(b2 + (192u << 10));                      // 32 KB
    float* dg1  = sums + 8192;                                      // 8 KB
    float* dg2  = dg1 + 2048;                                       // 8 KB

    k_prep<<<4096, 64, 0, stream>>>(p1, p2, pn, best, paircnt, sums);
    k_qcvt<<<4096, 256, 0, stream>>>(queue, qb);
    k_screen<<<dim3(64, 16), 256, 0, stream>>>(pn, qb, cm);
    k_rowmax<<<4096, 64, 0, stream>>>(cm, thrbuf);
    k_compact<<<8192, 256, 0, stream>>>(cm, thrbuf, paircnt, pairs);
    k_exact<<<1024, 256, 0, stream>>>(pn, queue, paircnt, pairs, best);
    k_gather<<<4096, 64, 0, stream>>>(queue, best, nnb);

    // M1 = nn1 @ p2n^T : rows -> loss[0..2047], cols -> loss[2048..4095]
    k_gemm_lse<<<dim3(32, 32), 256, 0, stream>>>(nnb, pn + 2048 * 128,
                                                 sums, sums + 2048, dg1);
    // M2 = nn2 @ p1n^T : rows -> loss[4096..6143], cols -> loss[6144..8191]
    k_gemm_lse<<<dim3(32, 32), 256, 0, stream>>>(nnb + 2048 * 128, pn,
                                                 sums + 4096, sums + 6144, dg2);
    k_final<<<32, 256, 0, stream>>>(sums, dg1, dg2, out);
}

// Round 5
// 419.121 us; speedup vs baseline: 1.0749x; 1.0749x over previous
//
#include <hip/hip_runtime.h>

#define S 132                 // padded LDS row stride (floats) for gemm tiles
#define SCALE 10.0f           // 1 / TEMPERATURE
#define EPS_MARGIN 0.008f     // 2 * (bf16 unit-dot hard error bound)
#define CAND_CAP 16384

typedef __attribute__((ext_vector_type(8))) short short8;
typedef __attribute__((ext_vector_type(4))) float floatx4;

#define MFMA16(a, b, c) __builtin_amdgcn_mfma_f32_16x16x32_bf16((a), (b), (c), 0, 0, 0)

// ---------- helpers ----------
__device__ __forceinline__ unsigned int ordered_bits(float f) {
    unsigned int b = __float_as_uint(f);
    return (b & 0x80000000u) ? ~b : (b | 0x80000000u);
}
__device__ __forceinline__ float from_ordered(unsigned int u) {
    return __uint_as_float((u & 0x80000000u) ? (u ^ 0x80000000u) : ~u);
}
__device__ __forceinline__ short bf_rne(float x) {   // fp32 -> bf16 bits, RNE
    unsigned int u = __float_as_uint(x);
    return (short)((u + 0x7FFFu + ((u >> 16) & 1u)) >> 16);
}
__device__ __forceinline__ float bf2f(short s) {
    return __uint_as_float(((unsigned int)(unsigned short)s) << 16);
}

// ---------- K1: l2-normalize p1,p2 -> pn fp32; init mbest/best/cnt/sums -----
__global__ void k_prep(const float* __restrict__ p1, const float* __restrict__ p2,
                       float* __restrict__ pn, unsigned int* __restrict__ mbest,
                       unsigned long long* __restrict__ best, unsigned int* __restrict__ cnt,
                       float* __restrict__ sums) {
    int row = blockIdx.x;               // 0..4095
    int t = threadIdx.x;                // 0..63
    const float* src = (row < 2048) ? (p1 + (size_t)row * 128)
                                    : (p2 + (size_t)(row - 2048) * 128);
    float2 v = ((const float2*)src)[t];
    float ss = v.x * v.x + v.y * v.y;
    #pragma unroll
    for (int o = 32; o; o >>= 1) ss += __shfl_xor(ss, o);
    float inv = 1.0f / sqrtf(ss);
    float2 o2; o2.x = v.x * inv; o2.y = v.y * inv;
    ((float2*)(pn + (size_t)row * 128))[t] = o2;
    if (t == 0) { mbest[row] = 0u; best[row] = 0ULL; if (row == 0) *cnt = 0u; }
    if (row < 128) sums[row * 64 + t] = 0.0f;
}

// ---------- K2: queue fp32 -> qb bf16 ----------
__global__ void k_qcvt(const float* __restrict__ queue, short* __restrict__ qb) {
    size_t i = ((size_t)blockIdx.x * 256 + threadIdx.x) * 8;
    float4 f0 = *(const float4*)(queue + i);
    float4 f1 = *(const float4*)(queue + i + 4);
    short8 o;
    o[0] = bf_rne(f0.x); o[1] = bf_rne(f0.y); o[2] = bf_rne(f0.z); o[3] = bf_rne(f0.w);
    o[4] = bf_rne(f1.x); o[5] = bf_rne(f1.y); o[6] = bf_rne(f1.z); o[7] = bf_rne(f1.w);
    *(short8*)(qb + i) = o;
}

// ---------- K3/K4: bf16 MFMA screen, two passes ------------------------------
// MODE 0: per-row bf16 max -> mbest.  MODE 1: per-q candidates above threshold.
// 1024 blocks (4/CU), 64 rows/block, XCD-swizzled qsplit so each XCD's
// resident blocks touch only 2 qsplits (2 MB of qb, L2-resident).
template <int MODE>
__global__ __launch_bounds__(256, 4) void k_screen(const float* __restrict__ pn,
                                                   const short* __restrict__ qb,
                                                   unsigned int* __restrict__ mbest,
                                                   unsigned int* __restrict__ cnt,
                                                   unsigned long long* __restrict__ cand) {
    int tid = threadIdx.x;
    int lane = tid & 63, wv = tid >> 6;
    int n16 = lane & 15, quad = lane >> 4;

    // XCD-aware swizzle: id%8 ~ XCD; each XCD covers 64 rowblocks x 2 qsplits.
    int id = blockIdx.x;                // 0..1023
    int xcd = id & 7;
    int j = id >> 3;                    // 0..127
    int rowblock = j & 63;
    int qsplit = xcd * 2 + (j >> 6);
    int rowbase = rowblock * 64;
    int qstart = qsplit * 4096 + wv * 1024;

    short8 A[4][4];
    #pragma unroll
    for (int rf = 0; rf < 4; ++rf) {
        const float* ap = pn + (size_t)(rowbase + rf * 16 + n16) * 128 + quad * 8;
        #pragma unroll
        for (int k = 0; k < 4; ++k) {
            float4 f0 = *(const float4*)(ap + 32 * k);
            float4 f1 = *(const float4*)(ap + 32 * k + 4);
            short8 a;
            a[0] = bf_rne(f0.x); a[1] = bf_rne(f0.y); a[2] = bf_rne(f0.z); a[3] = bf_rne(f0.w);
            a[4] = bf_rne(f1.x); a[5] = bf_rne(f1.y); a[6] = bf_rne(f1.z); a[7] = bf_rne(f1.w);
            A[rf][k] = a;
        }
    }

    float rmax[4][4], thr[4][4];
    #pragma unroll
    for (int rf = 0; rf < 4; ++rf)
        #pragma unroll
        for (int r = 0; r < 4; ++r) {
            if (MODE == 0) rmax[rf][r] = -1e30f;
            else thr[rf][r] = from_ordered(mbest[rowbase + rf * 16 + quad * 4 + r]) - EPS_MARGIN;
        }

    const short* lp = qb + (size_t)(qstart + n16) * 128 + quad * 8;
    short8 bc0 = *(const short8*)(lp), bc1 = *(const short8*)(lp + 32),
           bc2 = *(const short8*)(lp + 64), bc3 = *(const short8*)(lp + 96);
    floatx4 zero = {0.0f, 0.0f, 0.0f, 0.0f};

    for (int t = 0; t < 64; ++t) {
        const short* nlp = lp + 2048;   // prefetch next 16-q tile (tail over-read stays in ws)
        short8 bn0 = *(const short8*)(nlp), bn1 = *(const short8*)(nlp + 32),
               bn2 = *(const short8*)(nlp + 64), bn3 = *(const short8*)(nlp + 96);
        #pragma unroll
        for (int rf = 0; rf < 4; ++rf) {
            floatx4 acc = MFMA16(A[rf][0], bc0, zero);
            acc = MFMA16(A[rf][1], bc1, acc);
            acc = MFMA16(A[rf][2], bc2, acc);
            acc = MFMA16(A[rf][3], bc3, acc);
            if (MODE == 0) {
                #pragma unroll
                for (int r = 0; r < 4; ++r) rmax[rf][r] = fmaxf(rmax[rf][r], acc[r]);
            } else {
                #pragma unroll
                for (int r = 0; r < 4; ++r) {
                    if (acc[r] > thr[rf][r]) {
                        unsigned int pos = atomicAdd(cnt, 1u);
                        if (pos < CAND_CAP)
                            cand[pos] = ((unsigned long long)(unsigned int)(rowbase + rf * 16 + quad * 4 + r) << 32)
                                      | (unsigned int)(qstart + t * 16 + n16);
                    }
                }
            }
        }
        bc0 = bn0; bc1 = bn1; bc2 = bn2; bc3 = bn3;
        lp = nlp;
    }

    if (MODE == 0) {
        #pragma unroll
        for (int rf = 0; rf < 4; ++rf)
            #pragma unroll
            for (int r = 0; r < 4; ++r) {
                float v = rmax[rf][r];
                v = fmaxf(v, __shfl_xor(v, 1));
                v = fmaxf(v, __shfl_xor(v, 2));
                v = fmaxf(v, __shfl_xor(v, 4));
                v = fmaxf(v, __shfl_xor(v, 8));
                if (n16 == 0)
                    atomicMax(&mbest[rowbase + rf * 16 + quad * 4 + r], ordered_bits(v));
            }
    }
}

// ---------- K5: exact fp32 re-rank of candidates (one wave each) ----------
__global__ void k_rerank(const float* __restrict__ pn, const float* __restrict__ queue,
                         const unsigned int* __restrict__ cnt,
                         const unsigned long long* __restrict__ cand,
                         unsigned long long* __restrict__ best) {
    int widx = (blockIdx.x * 256 + threadIdx.x) >> 6;
    int lane = threadIdx.x & 63;
    unsigned int n = *cnt; if (n > CAND_CAP) n = CAND_CAP;
    if ((unsigned int)widx >= n) return;
    unsigned long long c = cand[widx];
    unsigned int row = (unsigned int)(c >> 32);
    unsigned int q = (unsigned int)c;
    float2 a = ((const float2*)(pn + (size_t)row * 128))[lane];
    float2 b = ((const float2*)(queue + (size_t)q * 128))[lane];
    float d = a.x * b.x + a.y * b.y;
    #pragma unroll
    for (int o = 32; o; o >>= 1) d += __shfl_xor(d, o);
    if (lane == 0) {
        unsigned long long pk = ((unsigned long long)ordered_bits(d) << 32)
                              | (unsigned long long)(unsigned int)(~q);
        atomicMax(&best[row], pk);
    }
}

// ---------- K6: gather nn rows from queue -> bf16 ----------
__global__ void k_gather(const float* __restrict__ queue,
                         const unsigned long long* __restrict__ best,
                         short* __restrict__ nnb) {
    int row = blockIdx.x;
    int t = threadIdx.x;
    unsigned int idx = ~(unsigned int)(best[row] & 0xFFFFFFFFull);
    idx &= 0xFFFFu;
    float2 v = ((const float2*)(queue + (size_t)idx * 128))[t];
    unsigned int pk = (unsigned int)(unsigned short)bf_rne(v.x)
                    | ((unsigned int)(unsigned short)bf_rne(v.y) << 16);
    ((unsigned int*)(nnb + (size_t)row * 128))[t] = pk;
}

// ---------- K7: fused A(bf16) @ B(fp32)^T -> exp-partial row/col sums --------
__global__ __launch_bounds__(256) void k_gemm_lse(const short* __restrict__ Ab,
                                                  const float* __restrict__ B,
                                                  float* __restrict__ rowsum,
                                                  float* __restrict__ colsum,
                                                  float* __restrict__ diag) {
    __shared__ __align__(16) float al[64 * S];
    __shared__ __align__(16) float bl[64 * S];
    __shared__ float red[64][17];
    int tid = threadIdx.x;
    const short8* asrc = (const short8*)(Ab + (size_t)blockIdx.x * 64 * 128);
    #pragma unroll
    for (int i = tid; i < 1024; i += 256) {
        short8 v = asrc[i];
        int r = i >> 4, c = (i & 15) * 8;
        float* dst = &al[r * S + c];
        #pragma unroll
        for (int j = 0; j < 8; ++j) dst[j] = bf2f(v[j]);
    }
    const float4* bsrc = (const float4*)(B + (size_t)blockIdx.y * 64 * 128);
    #pragma unroll
    for (int i = tid; i < 2048; i += 256) {
        int r = i >> 5, c = i & 31;
        *(float4*)&bl[r * S + c * 4] = bsrc[i];
    }
    __syncthreads();
    int ty = tid >> 4, tx = tid & 15;
    float acc[4][4] = {};
    #pragma unroll 2
    for (int k = 0; k < 128; k += 4) {
        float4 a[4], b[4];
        #pragma unroll
        for (int i = 0; i < 4; ++i) a[i] = *(const float4*)&al[(ty + 16 * i) * S + k];
        #pragma unroll
        for (int j = 0; j < 4; ++j) b[j] = *(const float4*)&bl[(tx + 16 * j) * S + k];
        #pragma unroll
        for (int i = 0; i < 4; ++i)
            #pragma unroll
            for (int j = 0; j < 4; ++j)
                acc[i][j] += a[i].x * b[j].x + a[i].y * b[j].y +
                             a[i].z * b[j].z + a[i].w * b[j].w;
    }
    int rowbase = blockIdx.x * 64, colbase = blockIdx.y * 64;

    float e[4][4], rs[4], cs[4];
    #pragma unroll
    for (int i = 0; i < 4; ++i) { rs[i] = 0.0f; cs[i] = 0.0f; }
    #pragma unroll
    for (int i = 0; i < 4; ++i)
        #pragma unroll
        for (int j = 0; j < 4; ++j) {
            e[i][j] = __expf(acc[i][j] * SCALE - 10.0f);
            rs[i] += e[i][j];
        }
    #pragma unroll
    for (int j = 0; j < 4; ++j)
        #pragma unroll
        for (int i = 0; i < 4; ++i) cs[j] += e[i][j];

    if (rowbase == colbase && ty == tx) {
        #pragma unroll
        for (int i = 0; i < 4; ++i) diag[rowbase + ty + 16 * i] = acc[i][i];
    }

    #pragma unroll
    for (int i = 0; i < 4; ++i) red[ty + 16 * i][tx] = rs[i];
    __syncthreads();
    if (tid < 64) {
        float s = 0.0f;
        #pragma unroll
        for (int x = 0; x < 16; ++x) s += red[tid][x];
        atomicAdd(&rowsum[rowbase + tid], s);
    }
    __syncthreads();
    #pragma unroll
    for (int j = 0; j < 4; ++j) red[tx + 16 * j][ty] = cs[j];
    __syncthreads();
    if (tid < 64) {
        float s = 0.0f;
        #pragma unroll
        for (int x = 0; x < 16; ++x) s += red[tid][x];
        atomicAdd(&colsum[colbase + tid], s);
    }
}

// ---------- K8: final loss ----------
__global__ void k_final(const float* __restrict__ sums,
                        const float* __restrict__ dg1, const float* __restrict__ dg2,
                        float* __restrict__ out) {
    int idx = blockIdx.x * 256 + threadIdx.x;    // 0..8191
    int seg = idx >> 11, r = idx & 2047;
    float s = sums[seg * 2048 + r];
    float d = (seg < 2) ? dg1[r] : dg2[r];
    out[idx] = 10.0f + logf(s) - d * SCALE;
}

extern "C" void kernel_launch(void* const* d_in, const int* in_sizes, int n_in,
                              void* d_out, int out_size, void* d_ws, size_t ws_size,
                              hipStream_t stream) {
    const float* p1    = (const float*)d_in[0];   // [2048,128]
    const float* p2    = (const float*)d_in[1];   // [2048,128]
    const float* queue = (const float*)d_in[2];   // [65536,128]
    float* out = (float*)d_out;                   // [8192]

    char* w = (char*)d_ws;                        // footprint ~19.3 MiB
    float* pn  = (float*)w;                               // 2 MB fp32 [4096,128]
    short* nnb = (short*)(w + (2u << 20));                // 1 MB bf16 [4096,128]
    short* qb  = (short*)(w + (3u << 20));                // 16 MB bf16 [65536,128]
    unsigned int* mbest = (unsigned int*)(w + (19u << 20));               // 16 KB
    unsigned long long* best = (unsigned long long*)(w + (19u << 20) + (16u << 10)); // 32 KB
    unsigned int* cnt = (unsigned int*)(w + (19u << 20) + (48u << 10));   // 64 B
    unsigned long long* cand = (unsigned long long*)(w + (19u << 20) + (48u << 10) + 64); // 128 KB
    float* sums = (float*)(w + (19u << 20) + (192u << 10));  // rs1,cs1,rs2,cs2: 32 KB
    float* dg1  = sums + 8192;                               // 8 KB
    float* dg2  = dg1 + 2048;                                // 8 KB

    k_prep<<<4096, 64, 0, stream>>>(p1, p2, pn, mbest, best, cnt, sums);
    k_qcvt<<<4096, 256, 0, stream>>>(queue, qb);
    k_screen<0><<<1024, 256, 0, stream>>>(pn, qb, mbest, cnt, cand);
    k_screen<1><<<1024, 256, 0, stream>>>(pn, qb, mbest, cnt, cand);
    k_rerank<<<4096, 256, 0, stream>>>(pn, queue, cnt, cand, best);
    k_gather<<<4096, 64, 0, stream>>>(queue, best, nnb);

    // M1 = nn1 @ p2n^T : rows -> loss[0..2047], cols -> loss[2048..4095]
    k_gemm_lse<<<dim3(32, 32), 256, 0, stream>>>(nnb, pn + 2048 * 128,
                                                 sums, sums + 2048, dg1);
    // M2 = nn2 @ p1n^T : rows -> loss[4096..6143], cols -> loss[6144..8191]
    k_gemm_lse<<<dim3(32, 32), 256, 0, stream>>>(nnb + 2048 * 128, pn,
                                                 sums + 4096, sums + 6144, dg2);
    k_final<<<32, 256, 0, stream>>>(sums, dg1, dg2, out);
}

// Round 6
// 298.676 us; speedup vs baseline: 1.5084x; 1.4033x over previous
//
#include <hip/hip_runtime.h>

#define S 132                 // padded LDS row stride (floats) for gemm tiles
#define SCALE 10.0f           // 1 / TEMPERATURE
#define EPS_MARGIN 0.008f     // 2 * (bf16 unit-dot hard error bound)
#define CAND_CAP 16384

typedef __attribute__((ext_vector_type(8))) short short8;
typedef __attribute__((ext_vector_type(4))) float floatx4;

#define MFMA16(a, b, c) __builtin_amdgcn_mfma_f32_16x16x32_bf16((a), (b), (c), 0, 0, 0)

// ---------- helpers ----------
__device__ __forceinline__ unsigned int ordered_bits(float f) {
    unsigned int b = __float_as_uint(f);
    return (b & 0x80000000u) ? ~b : (b | 0x80000000u);
}
__device__ __forceinline__ float from_ordered(unsigned int u) {
    return __uint_as_float((u & 0x80000000u) ? (u ^ 0x80000000u) : ~u);
}
__device__ __forceinline__ short bf_rne(float x) {   // fp32 -> bf16 bits, RNE
    unsigned int u = __float_as_uint(x);
    return (short)((u + 0x7FFFu + ((u >> 16) & 1u)) >> 16);
}
__device__ __forceinline__ float bf2f(short s) {
    return __uint_as_float(((unsigned int)(unsigned short)s) << 16);
}

// ---------- K1: l2-normalize p1,p2 -> pn fp32 + pnb bf16; init state --------
__global__ void k_prep(const float* __restrict__ p1, const float* __restrict__ p2,
                       float* __restrict__ pn, short* __restrict__ pnb,
                       unsigned int* __restrict__ mbest,
                       unsigned long long* __restrict__ best, unsigned int* __restrict__ cnt,
                       float* __restrict__ sums) {
    int row = blockIdx.x;               // 0..4095
    int t = threadIdx.x;                // 0..63
    const float* src = (row < 2048) ? (p1 + (size_t)row * 128)
                                    : (p2 + (size_t)(row - 2048) * 128);
    float2 v = ((const float2*)src)[t];
    float ss = v.x * v.x + v.y * v.y;
    #pragma unroll
    for (int o = 32; o; o >>= 1) ss += __shfl_xor(ss, o);
    float inv = 1.0f / sqrtf(ss);
    float2 o2; o2.x = v.x * inv; o2.y = v.y * inv;
    ((float2*)(pn + (size_t)row * 128))[t] = o2;
    unsigned int pk = (unsigned int)(unsigned short)bf_rne(o2.x)
                    | ((unsigned int)(unsigned short)bf_rne(o2.y) << 16);
    ((unsigned int*)(pnb + (size_t)row * 128))[t] = pk;
    if (t == 0) { mbest[row] = 0u; best[row] = 0ULL; if (row == 0) *cnt = 0u; }
    if (row < 128) sums[row * 64 + t] = 0.0f;
}

// ---------- K2: queue fp32 -> qb bf16 ----------
__global__ void k_qcvt(const float* __restrict__ queue, short* __restrict__ qb) {
    size_t i = ((size_t)blockIdx.x * 256 + threadIdx.x) * 8;
    float4 f0 = *(const float4*)(queue + i);
    float4 f1 = *(const float4*)(queue + i + 4);
    short8 o;
    o[0] = bf_rne(f0.x); o[1] = bf_rne(f0.y); o[2] = bf_rne(f0.z); o[3] = bf_rne(f0.w);
    o[4] = bf_rne(f1.x); o[5] = bf_rne(f1.y); o[6] = bf_rne(f1.z); o[7] = bf_rne(f1.w);
    *(short8*)(qb + i) = o;
}

// ---------- K3/K4: bf16 MFMA screen, two passes ------------------------------
// Block = 4 waves x SAME 1024-q strip (B shared via L1), wave w owns rows
// rowblk*512 + w*128 (A in 128 VGPRs). Grid 512 = 8 rowblocks x 64 qsplits,
// XCD-swizzled so each XCD touches 8 qsplits = 2 MB of qb (L2-resident).
// MODE 0: per-row bf16 max -> mbest. MODE 1: candidates above threshold.
template <int MODE>
__global__ __launch_bounds__(256, 2) void k_screen(const short* __restrict__ pnb,
                                                   const short* __restrict__ qb,
                                                   unsigned int* __restrict__ mbest,
                                                   unsigned int* __restrict__ cnt,
                                                   unsigned long long* __restrict__ cand) {
    int tid = threadIdx.x;
    int lane = tid & 63, wv = tid >> 6;
    int n16 = lane & 15, quad = lane >> 4;

    int id = blockIdx.x;                // 0..511
    int xcd = id & 7;
    int g = id >> 3;                    // 0..63
    int rowblk = g & 7;                 // 8 rowblocks of 512 rows
    int qsub = g >> 3;                  // 0..7
    int qsplit = xcd * 8 + qsub;        // 64 qsplits of 1024 q
    int rowbase = rowblk * 512 + wv * 128;
    int qstart = qsplit * 1024;

    // A fragments: 8 row-groups x 4 k-groups, direct bf16 short8 loads.
    short8 A[8][4];
    #pragma unroll
    for (int rf = 0; rf < 8; ++rf) {
        const short* ap = pnb + (size_t)(rowbase + rf * 16 + n16) * 128 + quad * 8;
        #pragma unroll
        for (int kk = 0; kk < 4; ++kk)
            A[rf][kk] = *(const short8*)(ap + kk * 32);
    }

    float rmax[8][4], thr[8][4];
    #pragma unroll
    for (int rf = 0; rf < 8; ++rf)
        #pragma unroll
        for (int r = 0; r < 4; ++r) {
            if (MODE == 0) rmax[rf][r] = -1e30f;
            else thr[rf][r] = from_ordered(mbest[rowbase + rf * 16 + quad * 4 + r]) - EPS_MARGIN;
        }

    const short* lp = qb + (size_t)(qstart + n16) * 128 + quad * 8;
    short8 bc0 = *(const short8*)(lp), bc1 = *(const short8*)(lp + 32),
           bc2 = *(const short8*)(lp + 64), bc3 = *(const short8*)(lp + 96);
    floatx4 zero = {0.0f, 0.0f, 0.0f, 0.0f};

    for (int t = 0; t < 64; ++t) {
        if ((t & 15) == 0) __syncthreads();   // keep waves converged for L1 B-sharing
        const short* nlp = lp + 2048;         // next 16-q tile (tail over-read stays in ws)
        short8 bn0 = *(const short8*)(nlp), bn1 = *(const short8*)(nlp + 32),
               bn2 = *(const short8*)(nlp + 64), bn3 = *(const short8*)(nlp + 96);
        #pragma unroll
        for (int rf = 0; rf < 8; ++rf) {
            floatx4 acc = MFMA16(A[rf][0], bc0, zero);
            acc = MFMA16(A[rf][1], bc1, acc);
            acc = MFMA16(A[rf][2], bc2, acc);
            acc = MFMA16(A[rf][3], bc3, acc);
            if (MODE == 0) {
                #pragma unroll
                for (int r = 0; r < 4; ++r) rmax[rf][r] = fmaxf(rmax[rf][r], acc[r]);
            } else {
                #pragma unroll
                for (int r = 0; r < 4; ++r) {
                    if (acc[r] > thr[rf][r]) {
                        unsigned int pos = atomicAdd(cnt, 1u);
                        if (pos < CAND_CAP)
                            cand[pos] = ((unsigned long long)(unsigned int)(rowbase + rf * 16 + quad * 4 + r) << 32)
                                      | (unsigned int)(qstart + t * 16 + n16);
                    }
                }
            }
        }
        bc0 = bn0; bc1 = bn1; bc2 = bn2; bc3 = bn3;
        lp = nlp;
    }

    if (MODE == 0) {
        #pragma unroll
        for (int rf = 0; rf < 8; ++rf)
            #pragma unroll
            for (int r = 0; r < 4; ++r) {
                float v = rmax[rf][r];
                v = fmaxf(v, __shfl_xor(v, 1));
                v = fmaxf(v, __shfl_xor(v, 2));
                v = fmaxf(v, __shfl_xor(v, 4));
                v = fmaxf(v, __shfl_xor(v, 8));
                if (n16 == 0)
                    atomicMax(&mbest[rowbase + rf * 16 + quad * 4 + r], ordered_bits(v));
            }
    }
}

// ---------- K5: exact fp32 re-rank of candidates (one wave each) ----------
__global__ void k_rerank(const float* __restrict__ pn, const float* __restrict__ queue,
                         const unsigned int* __restrict__ cnt,
                         const unsigned long long* __restrict__ cand,
                         unsigned long long* __restrict__ best) {
    int widx = (blockIdx.x * 256 + threadIdx.x) >> 6;
    int lane = threadIdx.x & 63;
    unsigned int n = *cnt; if (n > CAND_CAP) n = CAND_CAP;
    if ((unsigned int)widx >= n) return;
    unsigned long long c = cand[widx];
    unsigned int row = (unsigned int)(c >> 32);
    unsigned int q = (unsigned int)c;
    float2 a = ((const float2*)(pn + (size_t)row * 128))[lane];
    float2 b = ((const float2*)(queue + (size_t)q * 128))[lane];
    float d = a.x * b.x + a.y * b.y;
    #pragma unroll
    for (int o = 32; o; o >>= 1) d += __shfl_xor(d, o);
    if (lane == 0) {
        unsigned long long pk = ((unsigned long long)ordered_bits(d) << 32)
                              | (unsigned long long)(unsigned int)(~q);
        atomicMax(&best[row], pk);
    }
}

// ---------- K6: gather nn rows from queue -> bf16 ----------
__global__ void k_gather(const float* __restrict__ queue,
                         const unsigned long long* __restrict__ best,
                         short* __restrict__ nnb) {
    int row = blockIdx.x;
    int t = threadIdx.x;
    unsigned int idx = ~(unsigned int)(best[row] & 0xFFFFFFFFull);
    idx &= 0xFFFFu;
    float2 v = ((const float2*)(queue + (size_t)idx * 128))[t];
    unsigned int pk = (unsigned int)(unsigned short)bf_rne(v.x)
                    | ((unsigned int)(unsigned short)bf_rne(v.y) << 16);
    ((unsigned int*)(nnb + (size_t)row * 128))[t] = pk;
}

// ---------- K7: fused A(bf16) @ B(fp32)^T -> exp-partial row/col sums --------
__global__ __launch_bounds__(256) void k_gemm_lse(const short* __restrict__ Ab,
                                                  const float* __restrict__ B,
                                                  float* __restrict__ rowsum,
                                                  float* __restrict__ colsum,
                                                  float* __restrict__ diag) {
    __shared__ __align__(16) float al[64 * S];
    __shared__ __align__(16) float bl[64 * S];
    __shared__ float red[64][17];
    int tid = threadIdx.x;
    const short8* asrc = (const short8*)(Ab + (size_t)blockIdx.x * 64 * 128);
    #pragma unroll
    for (int i = tid; i < 1024; i += 256) {
        short8 v = asrc[i];
        int r = i >> 4, c = (i & 15) * 8;
        float* dst = &al[r * S + c];
        #pragma unroll
        for (int j = 0; j < 8; ++j) dst[j] = bf2f(v[j]);
    }
    const float4* bsrc = (const float4*)(B + (size_t)blockIdx.y * 64 * 128);
    #pragma unroll
    for (int i = tid; i < 2048; i += 256) {
        int r = i >> 5, c = i & 31;
        *(float4*)&bl[r * S + c * 4] = bsrc[i];
    }
    __syncthreads();
    int ty = tid >> 4, tx = tid & 15;
    float acc[4][4] = {};
    #pragma unroll 2
    for (int k = 0; k < 128; k += 4) {
        float4 a[4], b[4];
        #pragma unroll
        for (int i = 0; i < 4; ++i) a[i] = *(const float4*)&al[(ty + 16 * i) * S + k];
        #pragma unroll
        for (int j = 0; j < 4; ++j) b[j] = *(const float4*)&bl[(tx + 16 * j) * S + k];
        #pragma unroll
        for (int i = 0; i < 4; ++i)
            #pragma unroll
            for (int j = 0; j < 4; ++j)
                acc[i][j] += a[i].x * b[j].x + a[i].y * b[j].y +
                             a[i].z * b[j].z + a[i].w * b[j].w;
    }
    int rowbase = blockIdx.x * 64, colbase = blockIdx.y * 64;

    float e[4][4], rs[4], cs[4];
    #pragma unroll
    for (int i = 0; i < 4; ++i) { rs[i] = 0.0f; cs[i] = 0.0f; }
    #pragma unroll
    for (int i = 0; i < 4; ++i)
        #pragma unroll
        for (int j = 0; j < 4; ++j) {
            e[i][j] = __expf(acc[i][j] * SCALE - 10.0f);
            rs[i] += e[i][j];
        }
    #pragma unroll
    for (int j = 0; j < 4; ++j)
        #pragma unroll
        for (int i = 0; i < 4; ++i) cs[j] += e[i][j];

    if (rowbase == colbase && ty == tx) {
        #pragma unroll
        for (int i = 0; i < 4; ++i) diag[rowbase + ty + 16 * i] = acc[i][i];
    }

    #pragma unroll
    for (int i = 0; i < 4; ++i) red[ty + 16 * i][tx] = rs[i];
    __syncthreads();
    if (tid < 64) {
        float s = 0.0f;
        #pragma unroll
        for (int x = 0; x < 16; ++x) s += red[tid][x];
        atomicAdd(&rowsum[rowbase + tid], s);
    }
    __syncthreads();
    #pragma unroll
    for (int j = 0; j < 4; ++j) red[tx + 16 * j][ty] = cs[j];
    __syncthreads();
    if (tid < 64) {
        float s = 0.0f;
        #pragma unroll
        for (int x = 0; x < 16; ++x) s += red[tid][x];
        atomicAdd(&colsum[colbase + tid], s);
    }
}

// ---------- K8: final loss ----------
__global__ void k_final(const float* __restrict__ sums,
                        const float* __restrict__ dg1, const float* __restrict__ dg2,
                        float* __restrict__ out) {
    int idx = blockIdx.x * 256 + threadIdx.x;    // 0..8191
    int seg = idx >> 11, r = idx & 2047;
    float s = sums[seg * 2048 + r];
    float d = (seg < 2) ? dg1[r] : dg2[r];
    out[idx] = 10.0f + logf(s) - d * SCALE;
}

extern "C" void kernel_launch(void* const* d_in, const int* in_sizes, int n_in,
                              void* d_out, int out_size, void* d_ws, size_t ws_size,
                              hipStream_t stream) {
    const float* p1    = (const float*)d_in[0];   // [2048,128]
    const float* p2    = (const float*)d_in[1];   // [2048,128]
    const float* queue = (const float*)d_in[2];   // [65536,128]
    float* out = (float*)d_out;                   // [8192]

    char* w = (char*)d_ws;                        // footprint ~20.3 MiB (23.3 proven OK in r4)
    float* pn  = (float*)w;                               // 2 MB fp32 [4096,128]
    short* nnb = (short*)(w + (2u << 20));                // 1 MB bf16 [4096,128]
    short* qb  = (short*)(w + (3u << 20));                // 16 MB bf16 [65536,128]
    short* pnb = (short*)(w + (19u << 20));               // 1 MB bf16 [4096,128]
    char* b2 = w + (20u << 20);
    unsigned int* mbest = (unsigned int*)b2;                        // 16 KB
    unsigned long long* best = (unsigned long long*)(b2 + (16u << 10)); // 32 KB
    unsigned int* cnt = (unsigned int*)(b2 + (48u << 10));          // 64 B
    unsigned long long* cand = (unsigned long long*)(b2 + (64u << 10)); // 128 KB
    float* sums = (float*)(b2 + (192u << 10));                      // 32 KB
    float* dg1  = sums + 8192;                                      // 8 KB
    float* dg2  = dg1 + 2048;                                       // 8 KB

    k_prep<<<4096, 64, 0, stream>>>(p1, p2, pn, pnb, mbest, best, cnt, sums);
    k_qcvt<<<4096, 256, 0, stream>>>(queue, qb);
    k_screen<0><<<512, 256, 0, stream>>>(pnb, qb, mbest, cnt, cand);
    k_screen<1><<<512, 256, 0, stream>>>(pnb, qb, mbest, cnt, cand);
    k_rerank<<<4096, 256, 0, stream>>>(pn, queue, cnt, cand, best);
    k_gather<<<4096, 64, 0, stream>>>(queue, best, nnb);

    // M1 = nn1 @ p2n^T : rows -> loss[0..2047], cols -> loss[2048..4095]
    k_gemm_lse<<<dim3(32, 32), 256, 0, stream>>>(nnb, pn + 2048 * 128,
                                                 sums, sums + 2048, dg1);
    // M2 = nn2 @ p1n^T : rows -> loss[4096..6143], cols -> loss[6144..8191]
    k_gemm_lse<<<dim3(32, 32), 256, 0, stream>>>(nnb + 2048 * 128, pn,
                                                 sums + 4096, sums + 6144, dg2);
    k_final<<<32, 256, 0, stream>>>(sums, dg1, dg2, out);
}

// Round 7
// 296.831 us; speedup vs baseline: 1.5178x; 1.0062x over previous
//
#include <hip/hip_runtime.h>

#define S 132                 // padded LDS row stride (floats) for gemm tiles
#define SCALE 10.0f           // 1 / TEMPERATURE
#define EPS_MARGIN 0.008f     // 2 * (bf16 unit-dot hard error bound)
#define CAND_CAP 16384

typedef __attribute__((ext_vector_type(8))) short short8;
typedef __attribute__((ext_vector_type(4))) float floatx4;

#define MFMA16(a, b, c) __builtin_amdgcn_mfma_f32_16x16x32_bf16((a), (b), (c), 0, 0, 0)

// ---------- helpers ----------
__device__ __forceinline__ unsigned int ordered_bits(float f) {
    unsigned int b = __float_as_uint(f);
    return (b & 0x80000000u) ? ~b : (b | 0x80000000u);
}
__device__ __forceinline__ float from_ordered(unsigned int u) {
    return __uint_as_float((u & 0x80000000u) ? (u ^ 0x80000000u) : ~u);
}
__device__ __forceinline__ short bf_rne(float x) {   // fp32 -> bf16 bits, RNE
    unsigned int u = __float_as_uint(x);
    return (short)((u + 0x7FFFu + ((u >> 16) & 1u)) >> 16);
}
__device__ __forceinline__ float bf2f(short s) {
    return __uint_as_float(((unsigned int)(unsigned short)s) << 16);
}

// ---------- K1: l2-normalize p1,p2 -> pn fp32 + pnb bf16; init state --------
__global__ void k_prep(const float* __restrict__ p1, const float* __restrict__ p2,
                       float* __restrict__ pn, short* __restrict__ pnb,
                       unsigned int* __restrict__ mbest,
                       unsigned long long* __restrict__ best, unsigned int* __restrict__ cnt,
                       float* __restrict__ sums) {
    int row = blockIdx.x;               // 0..4095
    int t = threadIdx.x;                // 0..63
    const float* src = (row < 2048) ? (p1 + (size_t)row * 128)
                                    : (p2 + (size_t)(row - 2048) * 128);
    float2 v = ((const float2*)src)[t];
    float ss = v.x * v.x + v.y * v.y;
    #pragma unroll
    for (int o = 32; o; o >>= 1) ss += __shfl_xor(ss, o);
    float inv = 1.0f / sqrtf(ss);
    float2 o2; o2.x = v.x * inv; o2.y = v.y * inv;
    ((float2*)(pn + (size_t)row * 128))[t] = o2;
    unsigned int pk = (unsigned int)(unsigned short)bf_rne(o2.x)
                    | ((unsigned int)(unsigned short)bf_rne(o2.y) << 16);
    ((unsigned int*)(pnb + (size_t)row * 128))[t] = pk;
    if (t == 0) { mbest[row] = 0u; best[row] = 0ULL; if (row == 0) *cnt = 0u; }
    if (row < 128) sums[row * 64 + t] = 0.0f;
}

// ---------- K2: queue fp32 -> qb bf16 ----------
__global__ void k_qcvt(const float* __restrict__ queue, short* __restrict__ qb) {
    size_t i = ((size_t)blockIdx.x * 256 + threadIdx.x) * 8;
    float4 f0 = *(const float4*)(queue + i);
    float4 f1 = *(const float4*)(queue + i + 4);
    short8 o;
    o[0] = bf_rne(f0.x); o[1] = bf_rne(f0.y); o[2] = bf_rne(f0.z); o[3] = bf_rne(f0.w);
    o[4] = bf_rne(f1.x); o[5] = bf_rne(f1.y); o[6] = bf_rne(f1.z); o[7] = bf_rne(f1.w);
    *(short8*)(qb + i) = o;
}

// ---------- screen compute step: 16-q tile, k-outer / rf-inner (8-way ILP) ---
template <int MODE>
__device__ __forceinline__ void screen_tile(const short8 A[8][4],
                                            short8 b0, short8 b1, short8 b2, short8 b3,
                                            float rmax[8][4], const float thr[8][4],
                                            int qtile /* q index of this 16-q tile */,
                                            int rowbase, int quad, int n16,
                                            unsigned int* cnt, unsigned long long* cand) {
    floatx4 acc[8];
    floatx4 zero = {0.0f, 0.0f, 0.0f, 0.0f};
    #pragma unroll
    for (int rf = 0; rf < 8; ++rf) acc[rf] = MFMA16(A[rf][0], b0, zero);
    #pragma unroll
    for (int rf = 0; rf < 8; ++rf) acc[rf] = MFMA16(A[rf][1], b1, acc[rf]);
    #pragma unroll
    for (int rf = 0; rf < 8; ++rf) acc[rf] = MFMA16(A[rf][2], b2, acc[rf]);
    #pragma unroll
    for (int rf = 0; rf < 8; ++rf) acc[rf] = MFMA16(A[rf][3], b3, acc[rf]);

    if (MODE == 0) {
        #pragma unroll
        for (int rf = 0; rf < 8; ++rf)
            #pragma unroll
            for (int r = 0; r < 4; ++r) rmax[rf][r] = fmaxf(rmax[rf][r], acc[rf][r]);
    } else {
        float any = -1.0f;
        #pragma unroll
        for (int rf = 0; rf < 8; ++rf)
            #pragma unroll
            for (int r = 0; r < 4; ++r) any = fmaxf(any, acc[rf][r] - thr[rf][r]);
        if (__any(any > 0.0f)) {        // rare path: some candidate in this tile
            #pragma unroll
            for (int rf = 0; rf < 8; ++rf)
                #pragma unroll
                for (int r = 0; r < 4; ++r) {
                    if (acc[rf][r] > thr[rf][r]) {
                        unsigned int pos = atomicAdd(cnt, 1u);
                        if (pos < CAND_CAP)
                            cand[pos] = ((unsigned long long)(unsigned int)(rowbase + rf * 16 + quad * 4 + r) << 32)
                                      | (unsigned int)(qtile * 16 + n16);
                    }
                }
        }
    }
}

// ---------- K3/K4: bf16 MFMA screen, two passes ------------------------------
// Block = 4 waves x SAME 1024-q strip (B shared via L1/L2), wave w owns rows
// rowblk*512 + w*128 (A in 128 VGPRs). Grid 512 = 8 rowblocks x 64 qsplits,
// XCD-swizzled so each XCD touches 8 qsplits = 2 MB of qb (L2-resident).
// K-loop: manual 2x unroll, two B register sets (no copies), k-outer MFMA order.
template <int MODE>
__global__ __launch_bounds__(256, 2) void k_screen(const short* __restrict__ pnb,
                                                   const short* __restrict__ qb,
                                                   unsigned int* __restrict__ mbest,
                                                   unsigned int* __restrict__ cnt,
                                                   unsigned long long* __restrict__ cand) {
    int tid = threadIdx.x;
    int lane = tid & 63, wv = tid >> 6;
    int n16 = lane & 15, quad = lane >> 4;

    int id = blockIdx.x;                // 0..511
    int xcd = id & 7;
    int g = id >> 3;                    // 0..63
    int rowblk = g & 7;                 // 8 rowblocks of 512 rows
    int qsub = g >> 3;                  // 0..7
    int qsplit = xcd * 8 + qsub;        // 64 qsplits of 1024 q
    int rowbase = rowblk * 512 + wv * 128;
    int qstart = qsplit * 1024;

    // A fragments: 8 row-groups x 4 k-groups, direct bf16 short8 loads.
    short8 A[8][4];
    #pragma unroll
    for (int rf = 0; rf < 8; ++rf) {
        const short* ap = pnb + (size_t)(rowbase + rf * 16 + n16) * 128 + quad * 8;
        #pragma unroll
        for (int kk = 0; kk < 4; ++kk)
            A[rf][kk] = *(const short8*)(ap + kk * 32);
    }

    float rmax[8][4], thr[8][4];
    #pragma unroll
    for (int rf = 0; rf < 8; ++rf)
        #pragma unroll
        for (int r = 0; r < 4; ++r) {
            if (MODE == 0) rmax[rf][r] = -1e30f;
            else thr[rf][r] = from_ordered(mbest[rowbase + rf * 16 + quad * 4 + r]) - EPS_MARGIN;
        }

    const short* lp = qb + (size_t)(qstart + n16) * 128 + quad * 8;
    // B buffer set 0 <- tile 0
    short8 a0 = *(const short8*)(lp), a1 = *(const short8*)(lp + 32),
           a2 = *(const short8*)(lp + 64), a3 = *(const short8*)(lp + 96);

    for (int t = 0; t < 64; t += 2) {
        if ((t & 15) == 0) __syncthreads();    // keep waves converged for B sharing
        // B buffer set 1 <- tile t+1
        const short* p1p = lp + 2048;
        short8 b0 = *(const short8*)(p1p), b1 = *(const short8*)(p1p + 32),
               b2 = *(const short8*)(p1p + 64), b3 = *(const short8*)(p1p + 96);
        // compute tile t (set 0)
        screen_tile<MODE>(A, a0, a1, a2, a3, rmax, thr,
                          qstart / 16 + t, rowbase, quad, n16, cnt, cand);
        // B buffer set 0 <- tile t+2 (tail over-read lands in pnb region, unused)
        const short* p2p = lp + 4096;
        a0 = *(const short8*)(p2p); a1 = *(const short8*)(p2p + 32);
        a2 = *(const short8*)(p2p + 64); a3 = *(const short8*)(p2p + 96);
        // compute tile t+1 (set 1)
        screen_tile<MODE>(A, b0, b1, b2, b3, rmax, thr,
                          qstart / 16 + t + 1, rowbase, quad, n16, cnt, cand);
        lp += 4096;
    }

    if (MODE == 0) {
        #pragma unroll
        for (int rf = 0; rf < 8; ++rf)
            #pragma unroll
            for (int r = 0; r < 4; ++r) {
                float v = rmax[rf][r];
                v = fmaxf(v, __shfl_xor(v, 1));
                v = fmaxf(v, __shfl_xor(v, 2));
                v = fmaxf(v, __shfl_xor(v, 4));
                v = fmaxf(v, __shfl_xor(v, 8));
                if (n16 == 0)
                    atomicMax(&mbest[rowbase + rf * 16 + quad * 4 + r], ordered_bits(v));
            }
    }
}

// ---------- K5: exact fp32 re-rank of candidates (one wave each) ----------
__global__ void k_rerank(const float* __restrict__ pn, const float* __restrict__ queue,
                         const unsigned int* __restrict__ cnt,
                         const unsigned long long* __restrict__ cand,
                         unsigned long long* __restrict__ best) {
    int widx = (blockIdx.x * 256 + threadIdx.x) >> 6;
    int lane = threadIdx.x & 63;
    unsigned int n = *cnt; if (n > CAND_CAP) n = CAND_CAP;
    if ((unsigned int)widx >= n) return;
    unsigned long long c = cand[widx];
    unsigned int row = (unsigned int)(c >> 32);
    unsigned int q = (unsigned int)c;
    float2 a = ((const float2*)(pn + (size_t)row * 128))[lane];
    float2 b = ((const float2*)(queue + (size_t)q * 128))[lane];
    float d = a.x * b.x + a.y * b.y;
    #pragma unroll
    for (int o = 32; o; o >>= 1) d += __shfl_xor(d, o);
    if (lane == 0) {
        unsigned long long pk = ((unsigned long long)ordered_bits(d) << 32)
                              | (unsigned long long)(unsigned int)(~q);
        atomicMax(&best[row], pk);
    }
}

// ---------- K6: gather nn rows from queue -> bf16 ----------
__global__ void k_gather(const float* __restrict__ queue,
                         const unsigned long long* __restrict__ best,
                         short* __restrict__ nnb) {
    int row = blockIdx.x;
    int t = threadIdx.x;
    unsigned int idx = ~(unsigned int)(best[row] & 0xFFFFFFFFull);
    idx &= 0xFFFFu;
    float2 v = ((const float2*)(queue + (size_t)idx * 128))[t];
    unsigned int pk = (unsigned int)(unsigned short)bf_rne(v.x)
                    | ((unsigned int)(unsigned short)bf_rne(v.y) << 16);
    ((unsigned int*)(nnb + (size_t)row * 128))[t] = pk;
}

// ---------- K7: fused A(bf16) @ B(fp32)^T -> exp-partial row/col sums --------
__global__ __launch_bounds__(256) void k_gemm_lse(const short* __restrict__ Ab,
                                                  const float* __restrict__ B,
                                                  float* __restrict__ rowsum,
                                                  float* __restrict__ colsum,
                                                  float* __restrict__ diag) {
    __shared__ __align__(16) float al[64 * S];
    __shared__ __align__(16) float bl[64 * S];
    __shared__ float red[64][17];
    int tid = threadIdx.x;
    const short8* asrc = (const short8*)(Ab + (size_t)blockIdx.x * 64 * 128);
    #pragma unroll
    for (int i = tid; i < 1024; i += 256) {
        short8 v = asrc[i];
        int r = i >> 4, c = (i & 15) * 8;
        float* dst = &al[r * S + c];
        #pragma unroll
        for (int j = 0; j < 8; ++j) dst[j] = bf2f(v[j]);
    }
    const float4* bsrc = (const float4*)(B + (size_t)blockIdx.y * 64 * 128);
    #pragma unroll
    for (int i = tid; i < 2048; i += 256) {
        int r = i >> 5, c = i & 31;
        *(float4*)&bl[r * S + c * 4] = bsrc[i];
    }
    __syncthreads();
    int ty = tid >> 4, tx = tid & 15;
    float acc[4][4] = {};
    #pragma unroll 2
    for (int k = 0; k < 128; k += 4) {
        float4 a[4], b[4];
        #pragma unroll
        for (int i = 0; i < 4; ++i) a[i] = *(const float4*)&al[(ty + 16 * i) * S + k];
        #pragma unroll
        for (int j = 0; j < 4; ++j) b[j] = *(const float4*)&bl[(tx + 16 * j) * S + k];
        #pragma unroll
        for (int i = 0; i < 4; ++i)
            #pragma unroll
            for (int j = 0; j < 4; ++j)
                acc[i][j] += a[i].x * b[j].x + a[i].y * b[j].y +
                             a[i].z * b[j].z + a[i].w * b[j].w;
    }
    int rowbase = blockIdx.x * 64, colbase = blockIdx.y * 64;

    float e[4][4], rs[4], cs[4];
    #pragma unroll
    for (int i = 0; i < 4; ++i) { rs[i] = 0.0f; cs[i] = 0.0f; }
    #pragma unroll
    for (int i = 0; i < 4; ++i)
        #pragma unroll
        for (int j = 0; j < 4; ++j) {
            e[i][j] = __expf(acc[i][j] * SCALE - 10.0f);
            rs[i] += e[i][j];
        }
    #pragma unroll
    for (int j = 0; j < 4; ++j)
        #pragma unroll
        for (int i = 0; i < 4; ++i) cs[j] += e[i][j];

    if (rowbase == colbase && ty == tx) {
        #pragma unroll
        for (int i = 0; i < 4; ++i) diag[rowbase + ty + 16 * i] = acc[i][i];
    }

    #pragma unroll
    for (int i = 0; i < 4; ++i) red[ty + 16 * i][tx] = rs[i];
    __syncthreads();
    if (tid < 64) {
        float s = 0.0f;
        #pragma unroll
        for (int x = 0; x < 16; ++x) s += red[tid][x];
        atomicAdd(&rowsum[rowbase + tid], s);
    }
    __syncthreads();
    #pragma unroll
    for (int j = 0; j < 4; ++j) red[tx + 16 * j][ty] = cs[j];
    __syncthreads();
    if (tid < 64) {
        float s = 0.0f;
        #pragma unroll
        for (int x = 0; x < 16; ++x) s += red[tid][x];
        atomicAdd(&colsum[colbase + tid], s);
    }
}

// ---------- K8: final loss ----------
__global__ void k_final(const float* __restrict__ sums,
                        const float* __restrict__ dg1, const float* __restrict__ dg2,
                        float* __restrict__ out) {
    int idx = blockIdx.x * 256 + threadIdx.x;    // 0..8191
    int seg = idx >> 11, r = idx & 2047;
    float s = sums[seg * 2048 + r];
    float d = (seg < 2) ? dg1[r] : dg2[r];
    out[idx] = 10.0f + logf(s) - d * SCALE;
}

extern "C" void kernel_launch(void* const* d_in, const int* in_sizes, int n_in,
                              void* d_out, int out_size, void* d_ws, size_t ws_size,
                              hipStream_t stream) {
    const float* p1    = (const float*)d_in[0];   // [2048,128]
    const float* p2    = (const float*)d_in[1];   // [2048,128]
    const float* queue = (const float*)d_in[2];   // [65536,128]
    float* out = (float*)d_out;                   // [8192]

    char* w = (char*)d_ws;                        // footprint ~20.3 MiB
    float* pn  = (float*)w;                               // 2 MB fp32 [4096,128]
    short* nnb = (short*)(w + (2u << 20));                // 1 MB bf16 [4096,128]
    short* qb  = (short*)(w + (3u << 20));                // 16 MB bf16 [65536,128]
    short* pnb = (short*)(w + (19u << 20));               // 1 MB bf16 [4096,128]
    char* b2 = w + (20u << 20);
    unsigned int* mbest = (unsigned int*)b2;                        // 16 KB
    unsigned long long* best = (unsigned long long*)(b2 + (16u << 10)); // 32 KB
    unsigned int* cnt = (unsigned int*)(b2 + (48u << 10));          // 64 B
    unsigned long long* cand = (unsigned long long*)(b2 + (64u << 10)); // 128 KB
    float* sums = (float*)(b2 + (192u << 10));                      // 32 KB
    float* dg1  = sums + 8192;                                      // 8 KB
    float* dg2  = dg1 + 2048;                                       // 8 KB

    k_prep<<<4096, 64, 0, stream>>>(p1, p2, pn, pnb, mbest, best, cnt, sums);
    k_qcvt<<<4096, 256, 0, stream>>>(queue, qb);
    k_screen<0><<<512, 256, 0, stream>>>(pnb, qb, mbest, cnt, cand);
    k_screen<1><<<512, 256, 0, stream>>>(pnb, qb, mbest, cnt, cand);
    k_rerank<<<4096, 256, 0, stream>>>(pn, queue, cnt, cand, best);
    k_gather<<<4096, 64, 0, stream>>>(queue, best, nnb);

    // M1 = nn1 @ p2n^T : rows -> loss[0..2047], cols -> loss[2048..4095]
    k_gemm_lse<<<dim3(32, 32), 256, 0, stream>>>(nnb, pn + 2048 * 128,
                                                 sums, sums + 2048, dg1);
    // M2 = nn2 @ p1n^T : rows -> loss[4096..6143], cols -> loss[6144..8191]
    k_gemm_lse<<<dim3(32, 32), 256, 0, stream>>>(nnb + 2048 * 128, pn,
                                                 sums + 4096, sums + 6144, dg2);
    k_final<<<32, 256, 0, stream>>>(sums, dg1, dg2, out);
}